// Round 8
// baseline (125.321 us; speedup 1.0000x reference)
//
#include <hip/hip_runtime.h>
#include <math.h>

// ---------------- problem constants ----------------
namespace {
constexpr int Bn = 4, Sn = 8, Cn = 3, Himg = 256, Wimg = 256;
constexpr int Pn = 68, DS = 4, WIN = 8, STEPS = 10;
constexpr int HWi = Himg * Wimg;            // 65536
constexpr int NIMG = Bn * Sn;               // 32
constexpr int HD = Himg / DS, WD = Wimg / DS; // 64 x 64
constexpr int Kwin = (2 * WIN + 1) * (2 * WIN + 1); // 289
constexpr int PS = 40;                       // patch size (cols/rows used)
constexpr int PIT = 41;                      // LDS pitch (bank-stagger)
constexpr int HP = 19;                       // origin offset: cx0 = clamp(floor(px)) - HP
}

// ---------------- gray conversion ----------------
__global__ __launch_bounds__(256) void gray_kernel(const float* __restrict__ in,
                                                   float* __restrict__ gray) {
    int idx = blockIdx.x * blockDim.x + threadIdx.x;   // float4 index
    int total = NIMG * HWi / 4;
    if (idx >= total) return;
    int img = idx / (HWi / 4);
    int off = idx % (HWi / 4);
    const float* base = in + (size_t)img * 3 * HWi;
    float4 c0 = ((const float4*)(base))[off];
    float4 c1 = ((const float4*)(base + HWi))[off];
    float4 c2 = ((const float4*)(base + 2 * HWi))[off];
    float4 g;
    g.x = 0.299f * c0.x + 0.587f * c1.x + 0.114f * c2.x;
    g.y = 0.299f * c0.y + 0.587f * c1.y + 0.114f * c2.y;
    g.z = 0.299f * c0.z + 0.587f * c1.z + 0.114f * c2.z;
    g.w = 0.299f * c0.w + 0.587f * c1.w + 0.114f * c2.w;
    ((float4*)(gray + (size_t)img * HWi))[off] = g;
}

// ---------------- detector conv (3x3, stride 4, pad 0 == SAME here) ----------------
__global__ __launch_bounds__(256) void conv_kernel(const float* __restrict__ x,
                                                   const float* __restrict__ Wdet,
                                                   const float* __restrict__ bdet,
                                                   float* __restrict__ hm) {
    __shared__ float wsh[Pn * 27];
    __shared__ float bsh[Pn];
    __shared__ float insh[3][3][Wimg];
    int n = blockIdx.x >> 6;
    int oy = blockIdx.x & 63;
    int tid = threadIdx.x;
    for (int t = tid; t < Pn * 27; t += 256) wsh[t] = Wdet[t];
    if (tid < Pn) bsh[tid] = bdet[tid];
    for (int t = tid; t < 3 * 3 * Wimg; t += 256) {
        int c = t / (3 * Wimg);
        int r = (t / Wimg) % 3;
        int col = t % Wimg;
        insh[c][r][col] = x[(size_t)n * 3 * HWi + (size_t)c * HWi + (oy * 4 + r) * Wimg + col];
    }
    __syncthreads();
    int ox = tid & 63;
    int wid = tid >> 6;
    float in_reg[27];
    #pragma unroll
    for (int c = 0; c < 3; c++)
        #pragma unroll
        for (int ky = 0; ky < 3; ky++)
            #pragma unroll
            for (int kx = 0; kx < 3; kx++)
                in_reg[c * 9 + ky * 3 + kx] = insh[c][ky][ox * 4 + kx];
    #pragma unroll
    for (int i = 0; i < 17; i++) {
        int p = wid + i * 4;
        const float* w = &wsh[p * 27];
        float acc = bsh[p];
        #pragma unroll
        for (int j = 0; j < 27; j++) acc += w[j] * in_reg[j];
        hm[(size_t)n * Pn * 4096 + (size_t)p * 4096 + oy * 64 + ox] = acc;
    }
}

// ---------------- softmax / soft-argmax / scores ----------------
__global__ __launch_bounds__(256) void smax_kernel(const float* __restrict__ hm,
                                                   float* __restrict__ locs,
                                                   float* __restrict__ scos) {
    int row = blockIdx.x;   // n*Pn + p
    const float4* r = (const float4*)(hm + (size_t)row * 4096);
    int tid = threadIdx.x;
    float v[16];
    #pragma unroll
    for (int j = 0; j < 4; j++) {
        float4 q = r[tid + 256 * j];
        v[4 * j + 0] = q.x; v[4 * j + 1] = q.y; v[4 * j + 2] = q.z; v[4 * j + 3] = q.w;
    }
    float m = v[0];
    #pragma unroll
    for (int i = 1; i < 16; i++) m = fmaxf(m, v[i]);
    __shared__ float redm[4];
    #pragma unroll
    for (int o = 32; o; o >>= 1) m = fmaxf(m, __shfl_xor(m, o, 64));
    int wid = tid >> 6, lane = tid & 63;
    if (lane == 0) redm[wid] = m;
    __syncthreads();
    m = fmaxf(fmaxf(redm[0], redm[1]), fmaxf(redm[2], redm[3]));
    float s = 0.f, sx = 0.f, sy = 0.f;
    #pragma unroll
    for (int j = 0; j < 4; j++) {
        #pragma unroll
        for (int q = 0; q < 4; q++) {
            int e = (tid + 256 * j) * 4 + q;
            float ev = expf(v[4 * j + q] - m);
            s += ev;
            sx += ev * (float)(e & 63);
            sy += ev * (float)(e >> 6);
        }
    }
    #pragma unroll
    for (int o = 32; o; o >>= 1) {
        s  += __shfl_xor(s, o, 64);
        sx += __shfl_xor(sx, o, 64);
        sy += __shfl_xor(sy, o, 64);
    }
    __shared__ float reds[3][4];
    if (lane == 0) { reds[0][wid] = s; reds[1][wid] = sx; reds[2][wid] = sy; }
    __syncthreads();
    if (tid == 0) {
        float S_ = reds[0][0] + reds[0][1] + reds[0][2] + reds[0][3];
        float SX = reds[1][0] + reds[1][1] + reds[1][2] + reds[1][3];
        float SY = reds[2][0] + reds[2][1] + reds[2][2] + reds[2][3];
        locs[(size_t)row * 2 + 0] = SX / S_ * 4.0f;
        locs[(size_t)row * 2 + 1] = SY / S_ * 4.0f;
        scos[row] = m;
    }
}

// ---------------- DPP wave64 sum reduction (VALU-only) ----------------
template <int CTRL>
__device__ inline float dpp_add(float v) {
    int t = __builtin_amdgcn_update_dpp(0, __builtin_bit_cast(int, v), CTRL, 0xF, 0xF, true);
    return v + __builtin_bit_cast(float, t);
}

__device__ inline float wredw(float v) {
    v = dpp_add<0x111>(v);   // row_shr:1
    v = dpp_add<0x112>(v);   // row_shr:2
    v = dpp_add<0x114>(v);   // row_shr:4
    v = dpp_add<0x118>(v);   // row_shr:8
    v = dpp_add<0x142>(v);   // row_bcast:15
    v = dpp_add<0x143>(v);   // row_bcast:31
    int s = __builtin_amdgcn_readlane(__builtin_bit_cast(int, v), 63);
    return __builtin_bit_cast(float, s);
}

// ---------------- LK with LDS patch cache (1 wave/chain) ----------------
// Patch staged with clamp-composed indices: patch[r][c] = img[clampY(cy0+r)][clampX(cx0+c)].
// Template reads are provably inside the patch for any px,py (origin from clamped floor).
// GN iterations use a wave-uniform v-bounds check; global scalar fallback preserves
// correctness for unbounded v.
__device__ void lk_track_patch(const float* __restrict__ oldI, const float* __restrict__ newI,
                               float* __restrict__ oldP, float* __restrict__ newP,
                               float& px, float& py, const float* dxs, const float* dys,
                               float s4w, int lane) {
    const float XM = (float)(Wimg - 1.001);
    const float YM = (float)(Himg - 1.001);
    // ---- stage both patches (coalesced, each line once) ----
    int cx0 = min(max((int)floorf(px), 0), 255) - HP;
    int cy0 = min(max((int)floorf(py), 0), 255) - HP;
    __syncthreads();   // prior step's patch reads complete before overwrite
    #pragma unroll
    for (int i = 0; i < 25; i++) {
        int idx = lane + 64 * i;
        int rr = idx / PS;
        int cc = idx - rr * PS;
        int gr = min(max(cy0 + rr, 0), 255);
        int gc = min(max(cx0 + cc, 0), 255);
        int ga = gr * Wimg + gc;
        oldP[rr * PIT + cc] = oldI[ga];
        newP[rr * PIT + cc] = newI[ga];
    }
    __syncthreads();
    float I0[5], Ix[5], Iy[5], qx[5], qy[5];
    // ---- template phase from oldP ----
    {
        float wx[5], wy[5];
        int base[5];
        #pragma unroll
        for (int j = 0; j < 5; j++) {
            qx[j] = px + dxs[j];
            qy[j] = py + dys[j];
            float x = fminf(fmaxf(qx[j], 0.0f), XM);
            float y = fminf(fmaxf(qy[j], 0.0f), YM);
            float xf = floorf(x), yf = floorf(y);
            wx[j] = x - xf; wy[j] = y - yf;
            base[j] = ((int)yf - cy0) * PIT + ((int)xf - cx0);
        }
        float m0[5], m1[5], c0m[5], c00[5], c01[5], c0p[5], c1m[5], c10[5], c11[5], c1p[5], p0[5], p1[5];
        #pragma unroll
        for (int j = 0; j < 5; j++) {
            m0[j]  = oldP[base[j] - PIT];
            m1[j]  = oldP[base[j] - PIT + 1];
            c0m[j] = oldP[base[j] - 1];
            c00[j] = oldP[base[j]];
            c01[j] = oldP[base[j] + 1];
            c0p[j] = oldP[base[j] + 2];
            c1m[j] = oldP[base[j] + PIT - 1];
            c10[j] = oldP[base[j] + PIT];
            c11[j] = oldP[base[j] + PIT + 1];
            c1p[j] = oldP[base[j] + PIT + 2];
            p0[j]  = oldP[base[j] + 2 * PIT];
            p1[j]  = oldP[base[j] + 2 * PIT + 1];
        }
        #pragma unroll
        for (int j = 0; j < 5; j++) {
            float u = 1.0f - wx[j], t = 1.0f - wy[j];
            I0[j] = t * (u * c00[j] + wx[j] * c01[j]) + wy[j] * (u * c10[j] + wx[j] * c11[j]);
            float gx00 = 0.5f * (c01[j] - c0m[j]);
            float gx01 = 0.5f * (c0p[j] - c00[j]);
            float gx10 = 0.5f * (c11[j] - c1m[j]);
            float gx11 = 0.5f * (c1p[j] - c10[j]);
            Ix[j] = t * (u * gx00 + wx[j] * gx01) + wy[j] * (u * gx10 + wx[j] * gx11);
            float gy00 = 0.5f * (c10[j] - m0[j]);
            float gy01 = 0.5f * (c11[j] - m1[j]);
            float gy10 = 0.5f * (p0[j] - c00[j]);
            float gy11 = 0.5f * (p1[j] - c01[j]);
            Iy[j] = t * (u * gy00 + wx[j] * gy01) + wy[j] * (u * gy10 + wx[j] * gy11);
        }
        Ix[4] *= s4w;
        Iy[4] *= s4w;
    }
    float gxx = 0.f, gxy = 0.f, gyy = 0.f;
    #pragma unroll
    for (int j = 0; j < 5; j++) { gxx += Ix[j] * Ix[j]; gxy += Ix[j] * Iy[j]; gyy += Iy[j] * Iy[j]; }
    gxx = wredw(gxx); gxy = wredw(gxy); gyy = wredw(gyy);
    float det = gxx * gyy - gxy * gxy + 1e-6f;
    float A = gyy / det, Bv = -gxy / det, D = gxx / det;  // Ginv
    float vx = 0.f, vy = 0.f;
    // ---- Gauss-Newton loop: LDS fast path + global fallback ----
    for (int it = 0; it < STEPS; ++it) {
        // wave-uniform patch-bounds check on displaced window extremes
        float lox = fminf(fmaxf(px - 8.0f + vx, 0.0f), XM);
        float hix = fminf(fmaxf(px + 8.0f + vx, 0.0f), XM);
        float loy = fminf(fmaxf(py - 8.0f + vy, 0.0f), YM);
        float hiy = fminf(fmaxf(py + 8.0f + vy, 0.0f), YM);
        int lx = (int)floorf(lox) - cx0, hx = (int)floorf(hix) - cx0;
        int ly = (int)floorf(loy) - cy0, hy = (int)floorf(hiy) - cy0;
        bool fast = (lx >= 0) & (hx <= PS - 2) & (ly >= 0) & (hy <= PS - 2);
        float fx[5], fy[5], v00[5], v01[5], v10[5], v11[5];
        if (fast) {
            int bb[5];
            #pragma unroll
            for (int j = 0; j < 5; j++) {
                float x = fminf(fmaxf(qx[j] + vx, 0.0f), XM);
                float y = fminf(fmaxf(qy[j] + vy, 0.0f), YM);
                float xf = floorf(x), yf = floorf(y);
                fx[j] = x - xf; fy[j] = y - yf;
                bb[j] = ((int)yf - cy0) * PIT + ((int)xf - cx0);
            }
            #pragma unroll
            for (int j = 0; j < 5; j++) {
                v00[j] = newP[bb[j]];
                v01[j] = newP[bb[j] + 1];
                v10[j] = newP[bb[j] + PIT];
                v11[j] = newP[bb[j] + PIT + 1];
            }
        } else {
            #pragma unroll
            for (int j = 0; j < 5; j++) {
                float x = fminf(fmaxf(qx[j] + vx, 0.0f), XM);
                float y = fminf(fmaxf(qy[j] + vy, 0.0f), YM);
                float xf = floorf(x), yf = floorf(y);
                fx[j] = x - xf; fy[j] = y - yf;
                int xi = (int)xf, yi = (int)yf;
                int ad = yi * Wimg + xi;
                int d1 = (xi < Wimg - 1) ? 1 : 0;
                int d2 = (yi < Himg - 1) ? Wimg : 0;
                v00[j] = newI[ad];
                v01[j] = newI[ad + d1];
                v10[j] = newI[ad + d2];
                v11[j] = newI[ad + d2 + d1];
            }
        }
        float bx = 0.f, by = 0.f;
        #pragma unroll
        for (int j = 0; j < 5; j++) {
            float u = 1.0f - fx[j], t = 1.0f - fy[j];
            float I1 = t * (u * v00[j] + fx[j] * v01[j]) + fy[j] * (u * v10[j] + fx[j] * v11[j]);
            float err = I0[j] - I1;
            bx += err * Ix[j];
            by += err * Iy[j];
        }
        bx = wredw(bx); by = wredw(by);
        vx += A * bx + Bv * by;
        vy += Bv * bx + D * by;
    }
    px += vx; py += vy;
}

__global__ __launch_bounds__(64) void lk_patch_kernel(const float* __restrict__ gray,
                                                      const float* __restrict__ locs,
                                                      float* __restrict__ nextPts,
                                                      float* __restrict__ fbackPts,
                                                      float* __restrict__ backPts) {
    __shared__ float oldP[PS * PIT];
    __shared__ float newP[PS * PIT];
    int g = blockIdx.x;
    int typ = g / (Bn * Pn);
    int r = g % (Bn * Pn);
    int b = r / Pn;
    int p = r % Pn;
    int lane = threadIdx.x;
    const float* G = gray + (size_t)b * Sn * HWi;
    float dxs[5], dys[5];
    #pragma unroll
    for (int j = 0; j < 4; j++) {
        int k = lane + 64 * j;
        dxs[j] = (float)(k % 17 - 8);
        dys[j] = (float)(k / 17 - 8);
    }
    {
        int k4 = (lane < Kwin - 256) ? 256 + lane : 256;
        dxs[4] = (float)(k4 % 17 - 8);
        dys[4] = (float)(k4 / 17 - 8);
    }
    float s4w = (lane < Kwin - 256) ? 1.0f : 0.0f;
    auto LIDX = [&](int s) { return (((size_t)b * Sn + s) * Pn + p) * 2; };
    if (typ == 0) {
        float px = locs[LIDX(0)], py = locs[LIDX(0) + 1];
        if (lane == 0) { nextPts[LIDX(0)] = px; nextPts[LIDX(0) + 1] = py; }
        for (int s = 0; s < 7; s++) {
            lk_track_patch(G + s * HWi, G + (s + 1) * HWi, oldP, newP, px, py, dxs, dys, s4w, lane);
            if (lane == 0) { nextPts[LIDX(s + 1)] = px; nextPts[LIDX(s + 1) + 1] = py; }
        }
        if (lane == 0) { fbackPts[LIDX(7)] = px; fbackPts[LIDX(7) + 1] = py; }
        for (int i = 0; i < 7; i++) {
            lk_track_patch(G + (7 - i) * HWi, G + (6 - i) * HWi, oldP, newP, px, py, dxs, dys, s4w, lane);
            if (lane == 0) { fbackPts[LIDX(6 - i)] = px; fbackPts[LIDX(6 - i) + 1] = py; }
        }
    } else {
        float px = locs[LIDX(7)], py = locs[LIDX(7) + 1];
        if (lane == 0) { backPts[LIDX(7)] = px; backPts[LIDX(7) + 1] = py; }
        for (int i = 0; i < 7; i++) {
            lk_track_patch(G + (7 - i) * HWi, G + (6 - i) * HWi, oldP, newP, px, py, dxs, dys, s4w, lane);
            if (lane == 0) { backPts[LIDX(6 - i)] = px; backPts[LIDX(6 - i) + 1] = py; }
        }
    }
}

// ---------------- fallback (ws too small): on-the-fly gray, scalar gathers ----------------
__device__ inline float px_fly(const float* __restrict__ im, int idx) {
    return 0.299f * im[idx] + 0.587f * im[idx + HWi] + 0.114f * im[idx + 2 * HWi];
}

__device__ void lk_track_fly(const float* __restrict__ oldI, const float* __restrict__ newI,
                             float& px, float& py, const float* dxs, const float* dys,
                             float s4w) {
    const float XM = (float)(Wimg - 1.001);
    const float YM = (float)(Himg - 1.001);
    float I0[5], Ix[5], Iy[5], qx[5], qy[5];
    {
        float wx[5], wy[5];
        int am[5], a0[5], a1[5], ap[5], xm[5], x0[5], x1[5], xp[5];
        #pragma unroll
        for (int j = 0; j < 5; j++) {
            qx[j] = px + dxs[j]; qy[j] = py + dys[j];
            float x = fminf(fmaxf(qx[j], 0.0f), XM);
            float y = fminf(fmaxf(qy[j], 0.0f), YM);
            float x0f = floorf(x), y0f = floorf(y);
            wx[j] = x - x0f; wy[j] = y - y0f;
            int xi = (int)x0f, yi = (int)y0f;
            x0[j] = xi; x1[j] = min(xi + 1, Wimg - 1);
            xm[j] = max(xi - 1, 0); xp[j] = min(xi + 2, Wimg - 1);
            a0[j] = yi * Wimg;
            a1[j] = min(yi + 1, Himg - 1) * Wimg;
            am[j] = max(yi - 1, 0) * Wimg;
            ap[j] = min(yi + 2, Himg - 1) * Wimg;
        }
        #pragma unroll
        for (int j = 0; j < 5; j++) {
            float m0 = px_fly(oldI, am[j] + x0[j]), m1 = px_fly(oldI, am[j] + x1[j]);
            float c0m = px_fly(oldI, a0[j] + xm[j]), c00 = px_fly(oldI, a0[j] + x0[j]);
            float c01 = px_fly(oldI, a0[j] + x1[j]), c0p = px_fly(oldI, a0[j] + xp[j]);
            float c1m = px_fly(oldI, a1[j] + xm[j]), c10 = px_fly(oldI, a1[j] + x0[j]);
            float c11 = px_fly(oldI, a1[j] + x1[j]), c1p = px_fly(oldI, a1[j] + xp[j]);
            float p0 = px_fly(oldI, ap[j] + x0[j]), p1 = px_fly(oldI, ap[j] + x1[j]);
            float u = 1.0f - wx[j], t = 1.0f - wy[j];
            I0[j] = t * (u * c00 + wx[j] * c01) + wy[j] * (u * c10 + wx[j] * c11);
            Ix[j] = t * (u * 0.5f * (c01 - c0m) + wx[j] * 0.5f * (c0p - c00))
                  + wy[j] * (u * 0.5f * (c11 - c1m) + wx[j] * 0.5f * (c1p - c10));
            Iy[j] = t * (u * 0.5f * (c10 - m0) + wx[j] * 0.5f * (c11 - m1))
                  + wy[j] * (u * 0.5f * (p0 - c00) + wx[j] * 0.5f * (p1 - c01));
        }
        Ix[4] *= s4w; Iy[4] *= s4w;
    }
    float gxx = 0.f, gxy = 0.f, gyy = 0.f;
    #pragma unroll
    for (int j = 0; j < 5; j++) { gxx += Ix[j] * Ix[j]; gxy += Ix[j] * Iy[j]; gyy += Iy[j] * Iy[j]; }
    gxx = wredw(gxx); gxy = wredw(gxy); gyy = wredw(gyy);
    float det = gxx * gyy - gxy * gxy + 1e-6f;
    float A = gyy / det, Bv = -gxy / det, D = gxx / det;
    float vx = 0.f, vy = 0.f;
    for (int it = 0; it < STEPS; ++it) {
        float bx = 0.f, by = 0.f;
        #pragma unroll
        for (int j = 0; j < 5; j++) {
            float x = fminf(fmaxf(qx[j] + vx, 0.0f), XM);
            float y = fminf(fmaxf(qy[j] + vy, 0.0f), YM);
            float x0f = floorf(x), y0f = floorf(y);
            float fxx = x - x0f, fyy = y - y0f;
            int xi = (int)x0f, yi = (int)y0f;
            int ad = yi * Wimg + xi;
            int d1 = (xi < Wimg - 1) ? 1 : 0;
            int d2 = (yi < Himg - 1) ? Wimg : 0;
            float v00 = px_fly(newI, ad), v01 = px_fly(newI, ad + d1);
            float v10 = px_fly(newI, ad + d2), v11 = px_fly(newI, ad + d2 + d1);
            float u = 1.0f - fxx, t = 1.0f - fyy;
            float I1 = t * (u * v00 + fxx * v01) + fyy * (u * v10 + fxx * v11);
            float err = I0[j] - I1;
            bx += err * Ix[j];
            by += err * Iy[j];
        }
        bx = wredw(bx); by = wredw(by);
        vx += A * bx + Bv * by;
        vy += Bv * bx + D * by;
    }
    px += vx; py += vy;
}

__global__ __launch_bounds__(64) void lk_fly_kernel(const float* __restrict__ in,
                                                    const float* __restrict__ locs,
                                                    float* __restrict__ nextPts,
                                                    float* __restrict__ fbackPts,
                                                    float* __restrict__ backPts) {
    constexpr size_t FS = (size_t)3 * HWi;
    int g = blockIdx.x;
    int typ = g / (Bn * Pn);
    int r = g % (Bn * Pn);
    int b = r / Pn;
    int p = r % Pn;
    int lane = threadIdx.x;
    const float* G = in + (size_t)b * Sn * FS;
    float dxs[5], dys[5];
    #pragma unroll
    for (int j = 0; j < 4; j++) {
        int k = lane + 64 * j;
        dxs[j] = (float)(k % 17 - 8);
        dys[j] = (float)(k / 17 - 8);
    }
    {
        int k4 = (lane < Kwin - 256) ? 256 + lane : 256;
        dxs[4] = (float)(k4 % 17 - 8);
        dys[4] = (float)(k4 / 17 - 8);
    }
    float s4w = (lane < Kwin - 256) ? 1.0f : 0.0f;
    auto LIDX = [&](int s) { return (((size_t)b * Sn + s) * Pn + p) * 2; };
    if (typ == 0) {
        float px = locs[LIDX(0)], py = locs[LIDX(0) + 1];
        if (lane == 0) { nextPts[LIDX(0)] = px; nextPts[LIDX(0) + 1] = py; }
        for (int s = 0; s < 7; s++) {
            lk_track_fly(G + s * FS, G + (s + 1) * FS, px, py, dxs, dys, s4w);
            if (lane == 0) { nextPts[LIDX(s + 1)] = px; nextPts[LIDX(s + 1) + 1] = py; }
        }
        if (lane == 0) { fbackPts[LIDX(7)] = px; fbackPts[LIDX(7) + 1] = py; }
        for (int i = 0; i < 7; i++) {
            lk_track_fly(G + (7 - i) * FS, G + (6 - i) * FS, px, py, dxs, dys, s4w);
            if (lane == 0) { fbackPts[LIDX(6 - i)] = px; fbackPts[LIDX(6 - i) + 1] = py; }
        }
    } else {
        float px = locs[LIDX(7)], py = locs[LIDX(7) + 1];
        if (lane == 0) { backPts[LIDX(7)] = px; backPts[LIDX(7) + 1] = py; }
        for (int i = 0; i < 7; i++) {
            lk_track_fly(G + (7 - i) * FS, G + (6 - i) * FS, px, py, dxs, dys, s4w);
            if (lane == 0) { backPts[LIDX(6 - i)] = px; backPts[LIDX(6 - i) + 1] = py; }
        }
    }
}

// ---------------- launch ----------------
extern "C" void kernel_launch(void* const* d_in, const int* in_sizes, int n_in,
                              void* d_out, int out_size, void* d_ws, size_t ws_size,
                              hipStream_t stream) {
    const float* inputs = (const float*)d_in[0];
    const float* Wdet = (const float*)d_in[1];
    const float* bdet = (const float*)d_in[2];
    float* out = (float*)d_out;

    const size_t N_hm = (size_t)Bn * Sn * Pn * HD * WD;   // 8,912,896
    const size_t N_pts = (size_t)Bn * Sn * Pn * 2;        // 4352
    float* hm = out;
    float* locs = out + N_hm;
    float* scos = locs + N_pts;
    float* nextPts = scos + (size_t)Bn * Sn * Pn;
    float* fbackPts = nextPts + N_pts;
    float* backPts = fbackPts + N_pts;

    conv_kernel<<<NIMG * 64, 256, 0, stream>>>(inputs, Wdet, bdet, hm);
    smax_kernel<<<NIMG * Pn, 256, 0, stream>>>(hm, locs, scos);

    const size_t gray_bytes = (size_t)NIMG * HWi * sizeof(float);  // 8.4 MB
    if (ws_size >= gray_bytes) {
        float* gray = (float*)d_ws;
        gray_kernel<<<(NIMG * HWi / 4 + 255) / 256, 256, 0, stream>>>(inputs, gray);
        lk_patch_kernel<<<2 * Bn * Pn, 64, 0, stream>>>(gray, locs, nextPts, fbackPts, backPts);
    } else {
        lk_fly_kernel<<<2 * Bn * Pn, 64, 0, stream>>>(inputs, locs, nextPts, fbackPts, backPts);
    }
}